// Round 6
// baseline (324.982 us; speedup 1.0000x reference)
//
#include <hip/hip_runtime.h>

// Problem constants
#define IN_F   4096
#define OUT_F  4096
#define RK     32      // R_MIN
#define NB1    2048    // B1
#define MAXB   2048    // worst-case rows per bucket
#define LBATCH 10240   // B1 + B2*MULT
#define LRK    (LBATCH * RK)
#define NADP   160

typedef __attribute__((ext_vector_type(2))) __fp16 h2;
typedef __attribute__((ext_vector_type(8))) __fp16 h8;
typedef __attribute__((ext_vector_type(4))) float  f4;

// ws layout: cnt[64] | list[64*2048] | Rh[LRK] f16 | [Ath[160][32][4096] f16] | slabs[KS][LRK] f32

// ---------- prep: fused bin_rows (bx<64) + A transpose f32[a][k][c] -> f16 Ath[a][c][k]
__global__ __launch_bounds__(256) void prep(const int* __restrict__ wids,
                                            int* __restrict__ cnt,
                                            int* __restrict__ list,
                                            const float* __restrict__ A,
                                            __fp16* __restrict__ Ath) {
    int bx = blockIdx.x, t = threadIdx.x;
    if (bx < 64) {   // binning buckets
        __shared__ int lc;
        if (t == 0) lc = 0;
        __syncthreads();
        int* lg = list + bx * MAXB;
        if (bx < 32) {
            for (int i = t; i < NB1; i += 256)
                if (wids[i] == bx) lg[atomicAdd(&lc, 1)] = i;
        } else {
            for (int i = t; i < 2048; i += 256)
                if (32 + ((wids[NB1 + 4 * i] - 32) >> 2) == bx) lg[atomicAdd(&lc, 1)] = i;
        }
        __syncthreads();
        if (t == 0) cnt[bx] = lc;
        return;
    }
    // A transpose tile: adapter a, 256-k tile kt
    int bb = bx - 64;
    int a = bb >> 4, kt = bb & 15, k0 = kt * 256;
    __shared__ __fp16 T[32][264];
    const float* Ab = A + ((size_t)a * IN_F + k0) * RK;
    #pragma unroll
    for (int i = 0; i < 8; ++i) {
        int slot = t + 256 * i;
        int k = slot >> 3, c4 = (slot & 7) * 4;
        f4 v = *(const f4*)(Ab + (size_t)k * RK + c4);
        T[c4 + 0][k] = (__fp16)v.x; T[c4 + 1][k] = (__fp16)v.y;
        T[c4 + 2][k] = (__fp16)v.z; T[c4 + 3][k] = (__fp16)v.w;
    }
    __syncthreads();
    int c = t >> 3, j = t & 7;
    __fp16* Ao = Ath + ((size_t)a * RK + c) * IN_F + k0;
    #pragma unroll
    for (int i = 0; i < 4; ++i) {
        int kk = (j + 8 * i) * 8;
        *(h8*)(Ao + kk) = *(const h8*)&T[c][kk];
    }
}

__device__ __forceinline__ h8 cvt_x(f4 x0, f4 x1) {
    union { h8 v; h2 h[4]; } u;
    u.h[0] = __builtin_amdgcn_cvt_pkrtz(x0.x, x0.y);
    u.h[1] = __builtin_amdgcn_cvt_pkrtz(x0.z, x0.w);
    u.h[2] = __builtin_amdgcn_cvt_pkrtz(x1.x, x1.y);
    u.h[3] = __builtin_amdgcn_cvt_pkrtz(x1.z, x1.w);
    return u.v;
}

// per-wave inner loop: NST 32-k steps, no LDS, no barriers; fragments straight
// from global (Ath h8 contiguous, x 2xf4 + cvt). TA=false: scalar f32 A gathers.
template<int NST, bool TA>
__device__ __forceinline__ void s1_loop(const float* __restrict__ xp,
                                        const __fp16* __restrict__ A0,
                                        const __fp16* __restrict__ A1,
                                        const float* __restrict__ Araw, int m,
                                        f4& acc0, f4& acc1) {
    #pragma unroll 4
    for (int s = 0; s < NST; ++s) {
        h8 af0, af1;
        if constexpr (TA) {
            af0 = *(const h8*)(A0 + s * 32);
            af1 = *(const h8*)(A1 + s * 32);
        } else {
            #pragma unroll
            for (int j = 0; j < 8; ++j) {
                af0[j] = (__fp16)Araw[(size_t)(s * 32 + j) * RK + m];
                af1[j] = (__fp16)Araw[(size_t)(s * 32 + j) * RK + m + 16];
            }
        }
        f4 x0 = *(const f4*)(xp + s * 32);
        f4 x1 = *(const f4*)(xp + s * 32 + 4);
        h8 xa = cvt_x(x0, x1);
        acc0 = __builtin_amdgcn_mfma_f32_16x16x32_f16(xa, af0, acc0, 0, 0, 0);
        acc1 = __builtin_amdgcn_mfma_f32_16x16x32_f16(xa, af1, acc1, 0, 0, 0);
    }
}

// ---------------- Stage 1: block = (bucket, k-chunk, 16-row tile), 4 waves.
// p1: waves split k 4-ways (LDS reduce); p2: waves = 4 adapters. 6KB LDS total.
template<int KS, bool TA>
__global__ __launch_bounds__(256, 4) void s1(const float* __restrict__ x,
                                             const float* __restrict__ Araw,
                                             const __fp16* __restrict__ Ath,
                                             const int* __restrict__ cnt,
                                             const int* __restrict__ list,
                                             float* __restrict__ slabs) {
    constexpr int KCH = IN_F / KS;
    __shared__ f4 red[3][64][2];
    int t = threadIdx.x, lane = t & 63, wv = t >> 6, m = lane & 15, kg = lane >> 4;
    int bx = blockIdx.x, kc = blockIdx.y, rt = blockIdx.z;
    int p2 = bx >= 32;
    int n = cnt[bx];
    if (rt * 16 >= n) return;
    const int* lst = list + bx * MAXB;
    int it  = rt * 16 + m;
    int rid = lst[it < n ? it : n - 1];
    int xrow = rid + (p2 ? NB1 : 0);
    float* slab = slabs + (size_t)kc * LRK;
    f4 acc0 = {0.f, 0.f, 0.f, 0.f}, acc1 = {0.f, 0.f, 0.f, 0.f};

    if (p2) {
        int a  = 32 + 4 * (bx - 32) + wv;
        int kb = kc * KCH + kg * 8;
        const float*  xp = x + (size_t)xrow * IN_F + kb;
        const __fp16* A0 = Ath + ((size_t)a * RK + m) * IN_F + kb;
        const __fp16* A1 = A0 + (size_t)16 * IN_F;
        const float*  Ar = Araw + ((size_t)a * IN_F + kb) * RK;
        s1_loop<KCH / 32, TA>(xp, A0, A1, Ar, m, acc0, acc1);
        #pragma unroll
        for (int q = 0; q < 4; ++q) {
            int itq = rt * 16 + 4 * kg + q;
            if (itq < n) {
                int ridq = lst[itq];
                float* sp = slab + (size_t)(NB1 + 4 * ridq + wv) * RK + m;
                sp[0]  = acc0[q];
                sp[16] = acc1[q];
            }
        }
    } else {
        int a  = bx;
        int kb = kc * KCH + wv * (KCH / 4) + kg * 8;
        const float*  xp = x + (size_t)xrow * IN_F + kb;
        const __fp16* A0 = Ath + ((size_t)a * RK + m) * IN_F + kb;
        const __fp16* A1 = A0 + (size_t)16 * IN_F;
        const float*  Ar = Araw + ((size_t)a * IN_F + kb) * RK;
        s1_loop<KCH / 128, TA>(xp, A0, A1, Ar, m, acc0, acc1);
        if (wv > 0) { red[wv - 1][lane][0] = acc0; red[wv - 1][lane][1] = acc1; }
        __syncthreads();
        if (wv == 0) {
            #pragma unroll
            for (int j = 0; j < 3; ++j) { acc0 += red[j][lane][0]; acc1 += red[j][lane][1]; }
            #pragma unroll
            for (int q = 0; q < 4; ++q) {
                int itq = rt * 16 + 4 * kg + q;
                if (itq < n) {
                    int ridq = lst[itq];
                    float* sp = slab + (size_t)ridq * RK + m;
                    sp[0]  = acc0[q];
                    sp[16] = acc1[q];
                }
            }
        }
    }
}

// ---------------- slab reduction -> Rh f16 (RTN casts, matches ref's y rounding)
template<int KS>
__global__ __launch_bounds__(256) void reduceR(const float* __restrict__ slabs,
                                               __fp16* __restrict__ Rh) {
    int i = (blockIdx.x * 256 + threadIdx.x) * 8;
    f4 a = *(const f4*)(slabs + i);
    f4 b = *(const f4*)(slabs + i + 4);
    #pragma unroll
    for (int s = 1; s < KS; ++s) {
        a += *(const f4*)(slabs + (size_t)s * LRK + i);
        b += *(const f4*)(slabs + (size_t)s * LRK + i + 4);
    }
    h8 o;
    o[0] = (__fp16)a.x; o[1] = (__fp16)a.y; o[2] = (__fp16)a.z; o[3] = (__fp16)a.w;
    o[4] = (__fp16)b.x; o[5] = (__fp16)b.y; o[6] = (__fp16)b.z; o[7] = (__fp16)b.w;
    *(h8*)(Rh + i) = o;
}

// ---------------- Stage 2 (round-4/5 verified): one wave per (bucket, 32-col
// tile); B fragments register-resident, R fragments 16B loads. No LDS/barriers.
__global__ __launch_bounds__(256, 4) void s2(const __fp16* __restrict__ Rh,
                                             const float* __restrict__ B,
                                             const int* __restrict__ cnt,
                                             const int* __restrict__ list,
                                             float* __restrict__ out) {
    int lane = threadIdx.x & 63, wv = threadIdx.x >> 6;
    int g   = blockIdx.x;
    int oct = blockIdx.y * 4 + wv;
    int p2  = g >= 32;
    int n = cnt[g];
    if (n == 0) return;
    const int* lst = list + g * MAXB;
    int m = lane & 15, kg = lane >> 4;
    int oc0 = oct * 32;
    int nkc = p2 ? 4 : 1;

    h8 bf[4][2];
    #pragma unroll
    for (int kcb = 0; kcb < 4; ++kcb) {
        if (kcb < nkc) {
            int a = p2 ? (32 + 4 * (g - 32) + kcb) : g;
            const float* Bb = B + ((size_t)a * RK + kg * 8) * OUT_F + oc0 + m;
            #pragma unroll
            for (int ct = 0; ct < 2; ++ct) {
                union { h8 v; h2 h[4]; } u2;
                #pragma unroll
                for (int jj = 0; jj < 4; ++jj) {
                    float e0 = Bb[(size_t)(2 * jj) * OUT_F + ct * 16];
                    float e1 = Bb[(size_t)(2 * jj + 1) * OUT_F + ct * 16];
                    u2.h[jj] = __builtin_amdgcn_cvt_pkrtz(e0, e1);
                }
                bf[kcb][ct] = u2.v;
            }
        }
    }

    for (int rt = 0; rt * 16 < n; ++rt) {
        int it = rt * 16 + m;
        int ridm = lst[it < n ? it : n - 1];
        f4 acc0 = {0.f, 0.f, 0.f, 0.f}, acc1 = {0.f, 0.f, 0.f, 0.f};
        #pragma unroll
        for (int kcb = 0; kcb < 4; ++kcb) {
            if (kcb < nkc) {
                int rrow = p2 ? (NB1 + 4 * ridm + kcb) : ridm;
                h8 rf = *(const h8*)(Rh + (size_t)rrow * RK + kg * 8);
                acc0 = __builtin_amdgcn_mfma_f32_16x16x32_f16(rf, bf[kcb][0], acc0, 0, 0, 0);
                acc1 = __builtin_amdgcn_mfma_f32_16x16x32_f16(rf, bf[kcb][1], acc1, 0, 0, 0);
            }
        }
        #pragma unroll
        for (int q = 0; q < 4; ++q) {
            int itq = rt * 16 + 4 * kg + q;
            if (itq < n) {
                int ridq = lst[itq];
                int orow = p2 ? (NB1 + ridq) : ridq;
                float* op = out + (size_t)orow * OUT_F + oc0 + m;
                op[0]  = 2.f * acc0[q];
                op[16] = 2.f * acc1[q];
            }
        }
    }
}

extern "C" void kernel_launch(void* const* d_in, const int* in_sizes, int n_in,
                              void* d_out, int out_size, void* d_ws, size_t ws_size,
                              hipStream_t stream) {
    const float* x    = (const float*)d_in[0];
    const int*   wids = (const int*)  d_in[2];
    const float* A    = (const float*)d_in[3];
    const float* Bm   = (const float*)d_in[4];
    float* out = (float*)d_out;

    int* wsI  = (int*)d_ws;
    int* cnt  = wsI;
    int* list = wsI + 64;
    __fp16* Rh = (__fp16*)(list + 64 * MAXB);
    char* p = (char*)Rh + (size_t)LRK * sizeof(__fp16);

    size_t fixed  = (size_t)(64 + 64 * MAXB) * sizeof(int) + (size_t)LRK * sizeof(__fp16);
    size_t athB   = (size_t)NADP * RK * IN_F * sizeof(__fp16);   // 41.9 MB
    size_t slab1  = (size_t)LRK * sizeof(float);                 // 1.31 MB

    bool ta = false; int ks = 4;
    if      (ws_size >= fixed + athB + 8 * slab1) { ta = true;  ks = 8; }
    else if (ws_size >= fixed + athB + 4 * slab1) { ta = true;  ks = 4; }
    else if (ws_size >= fixed + 8 * slab1)        { ta = false; ks = 8; }
    else                                          { ta = false; ks = 4; }

    __fp16* Ath  = ta ? (__fp16*)p : nullptr;
    float* slabs = (float*)(ta ? (p + athB) : p);

    prep<<<dim3(ta ? 64 + NADP * 16 : 64), dim3(256), 0, stream>>>(wids, cnt, list, A, Ath);
    if (ta) {
        if (ks == 8) s1<8, true ><<<dim3(64, 8, 8), dim3(256), 0, stream>>>(x, A, Ath, cnt, list, slabs);
        else         s1<4, true ><<<dim3(64, 4, 8), dim3(256), 0, stream>>>(x, A, Ath, cnt, list, slabs);
    } else {
        if (ks == 8) s1<8, false><<<dim3(64, 8, 8), dim3(256), 0, stream>>>(x, A, Ath, cnt, list, slabs);
        else         s1<4, false><<<dim3(64, 4, 8), dim3(256), 0, stream>>>(x, A, Ath, cnt, list, slabs);
    }
    if (ks == 8) reduceR<8><<<dim3(160), dim3(256), 0, stream>>>(slabs, Rh);
    else         reduceR<4><<<dim3(160), dim3(256), 0, stream>>>(slabs, Rh);
    s2<<<dim3(64, 32), dim3(256), 0, stream>>>(Rh, Bm, cnt, list, out);
}